// Round 1
// baseline (57.979 us; speedup 1.0000x reference)
//
#include <hip/hip_runtime.h>
#include <math.h>

#define NB 65536   // batch

// ---------------------------------------------------------------------------
// Kernel A: build W = U_layers * diag(zeta_j) (16x16 complex), zero BN accums.
// Column-parallel: thread j owns column j of U in registers (fully unrolled
// so all indices are compile-time -> stays in VGPRs).
// ---------------------------------------------------------------------------
__global__ __launch_bounds__(64) void build_unitary_kernel(
        const float* __restrict__ weights,   // [3][4][2]
        float2* __restrict__ W_out,          // [16*16]
        double* __restrict__ bn_acc) {       // [8]
    int t = threadIdx.x;
    if (t >= 16 && t < 24) bn_acc[t - 16] = 0.0;
    if (t >= 16) return;

    float cr[16], ci[16];
#pragma unroll
    for (int i = 0; i < 16; ++i) { cr[i] = (i == t) ? 1.0f : 0.0f; ci[i] = 0.0f; }

    for (int l = 0; l < 3; ++l) {
#pragma unroll
        for (int w = 0; w < 4; ++w) {
            const int mask = 8 >> w;        // wire w -> bit (3-w)
            // RX(weights[l][w][0])
            float tx = weights[(l * 4 + w) * 2 + 0] * 0.5f;
            float c = cosf(tx), s = sinf(tx);
#pragma unroll
            for (int i = 0; i < 16; ++i) {
                if (!(i & mask)) {
                    const int ip = i | mask;
                    float a0r = cr[i], a0i = ci[i], a1r = cr[ip], a1i = ci[ip];
                    // [[c, -i s],[-i s, c]]
                    cr[i]  = c * a0r + s * a1i;
                    ci[i]  = c * a0i - s * a1r;
                    cr[ip] = c * a1r + s * a0i;
                    ci[ip] = c * a1i - s * a0r;
                }
            }
            // RZ(weights[l][w][1]) = diag(e^{-i tz}, e^{+i tz})
            float tz = weights[(l * 4 + w) * 2 + 1] * 0.5f;
            float ce = cosf(tz), se = sinf(tz);
#pragma unroll
            for (int i = 0; i < 16; ++i) {
                if (!(i & mask)) {
                    const int ip = i | mask;
                    float a0r = cr[i], a0i = ci[i], a1r = cr[ip], a1i = ci[ip];
                    cr[i]  = ce * a0r + se * a0i;
                    ci[i]  = ce * a0i - se * a0r;
                    cr[ip] = ce * a1r - se * a1i;
                    ci[ip] = ce * a1i + se * a1r;
                }
            }
        }
        // CNOT ring: control w, target (w+1)%4
#pragma unroll
        for (int w = 0; w < 4; ++w) {
            const int mc = 8 >> w;
            const int mt = 8 >> ((w + 1) & 3);
#pragma unroll
            for (int i = 0; i < 16; ++i) {
                if ((i & mc) && !(i & mt)) {
                    const int ip = i | mt;
                    float tr = cr[i], ti = ci[i];
                    cr[i] = cr[ip]; ci[i] = ci[ip];
                    cr[ip] = tr;   ci[ip] = ti;
                }
            }
        }
    }

    // fold zeta_j = (-i)^popcount(j) into column j
    int p = __popc(t) & 3;
#pragma unroll
    for (int i = 0; i < 16; ++i) {
        float wr, wi;
        if (p == 0)      { wr =  cr[i]; wi =  ci[i]; }
        else if (p == 1) { wr =  ci[i]; wi = -cr[i]; }
        else if (p == 2) { wr = -cr[i]; wi = -ci[i]; }
        else             { wr = -ci[i]; wi =  cr[i]; }
        W_out[i * 16 + t] = make_float2(wr, wi);
    }
}

// ---------------------------------------------------------------------------
// Kernel 1: avg-pool 6x6 (first 24x24) + pre-FC -> encoded angles [B][4].
// 4 threads per image: thread handles one 6-row band (4 pooling windows),
// butterfly over the 4-lane group combines the FC partials.
// ---------------------------------------------------------------------------
__global__ __launch_bounds__(256) void pool_fc_kernel(
        const float* __restrict__ x,        // [B][1][28][28]
        const float* __restrict__ pre_w,    // [4][16]
        const float* __restrict__ pre_b,    // [4]
        float4* __restrict__ encoded) {     // [B]
    int t = blockIdx.x * 256 + threadIdx.x;     // NB*4 threads
    int b = t >> 2;
    int h1 = t & 3;
    const float* img = x + (size_t)b * 784 + (size_t)(h1 * 6) * 28;

    float cs0 = 0.f, cs1 = 0.f, cs2 = 0.f, cs3 = 0.f;
#pragma unroll
    for (int r = 0; r < 6; ++r) {
        const float4* row = (const float4*)(img + r * 28);  // 16B-aligned
        float4 f0 = row[0], f1 = row[1], f2 = row[2];
        float4 f3 = row[3], f4 = row[4], f5 = row[5];
        cs0 += f0.x + f0.y + f0.z + f0.w + f1.x + f1.y;   // cols 0..5
        cs1 += f1.z + f1.w + f2.x + f2.y + f2.z + f2.w;   // cols 6..11
        cs2 += f3.x + f3.y + f3.z + f3.w + f4.x + f4.y;   // cols 12..17
        cs3 += f4.z + f4.w + f5.x + f5.y + f5.z + f5.w;   // cols 18..23
    }
    const float inv36 = 1.0f / 36.0f;
    cs0 *= inv36; cs1 *= inv36; cs2 *= inv36; cs3 *= inv36;

    const int k0 = h1 * 4;
    float p0 = cs0 * pre_w[0 * 16 + k0] + cs1 * pre_w[0 * 16 + k0 + 1] +
               cs2 * pre_w[0 * 16 + k0 + 2] + cs3 * pre_w[0 * 16 + k0 + 3];
    float p1 = cs0 * pre_w[1 * 16 + k0] + cs1 * pre_w[1 * 16 + k0 + 1] +
               cs2 * pre_w[1 * 16 + k0 + 2] + cs3 * pre_w[1 * 16 + k0 + 3];
    float p2 = cs0 * pre_w[2 * 16 + k0] + cs1 * pre_w[2 * 16 + k0 + 1] +
               cs2 * pre_w[2 * 16 + k0 + 2] + cs3 * pre_w[2 * 16 + k0 + 3];
    float p3 = cs0 * pre_w[3 * 16 + k0] + cs1 * pre_w[3 * 16 + k0 + 1] +
               cs2 * pre_w[3 * 16 + k0 + 2] + cs3 * pre_w[3 * 16 + k0 + 3];

    // combine the 4 bands of one image (lanes 4a..4a+3)
    p0 += __shfl_xor(p0, 1); p0 += __shfl_xor(p0, 2);
    p1 += __shfl_xor(p1, 1); p1 += __shfl_xor(p1, 2);
    p2 += __shfl_xor(p2, 1); p2 += __shfl_xor(p2, 2);
    p3 += __shfl_xor(p3, 1); p3 += __shfl_xor(p3, 2);

    if ((threadIdx.x & 3) == 0) {
        encoded[b] = make_float4(p0 + pre_b[0], p1 + pre_b[1],
                                 p2 + pre_b[2], p3 + pre_b[3]);
    }
}

// ---------------------------------------------------------------------------
// Kernel 3: per image: product-state magnitudes m[16] -> state = W m ->
// probs -> <Z_w> -> logits -> d_out; block-reduced BN partial sums -> atomics.
// ---------------------------------------------------------------------------
__global__ __launch_bounds__(256) void quantum_kernel(
        const float4* __restrict__ encoded,  // [B]
        const float2* __restrict__ Wu,       // [256]
        const float* __restrict__ fc_w,      // [4][4]
        const float* __restrict__ fc_b,      // [4]
        float4* __restrict__ out,            // [B] logits
        double* __restrict__ bn_acc) {       // [8]
    __shared__ float2 Wl[256];
    int tid = threadIdx.x;
    Wl[tid] = Wu[tid];
    __syncthreads();

    int b = blockIdx.x * 256 + tid;
    float4 e = encoded[b];
    float s0, c0, s1, c1, s2, c2, s3, c3;
    __sincosf(e.x * 0.5f, &s0, &c0);
    __sincosf(e.y * 0.5f, &s1, &c1);
    __sincosf(e.z * 0.5f, &s2, &c2);
    __sincosf(e.w * 0.5f, &s3, &c3);

    float m01[4] = { c0 * c1, c0 * s1, s0 * c1, s0 * s1 };
    float m23[4] = { c2 * c3, c2 * s3, s2 * c3, s2 * s3 };
    float m[16];
#pragma unroll
    for (int i = 0; i < 16; ++i) m[i] = m01[i >> 2] * m23[i & 3];

    float z0 = 0.f, z1 = 0.f, z2 = 0.f, z3 = 0.f;
#pragma unroll
    for (int i = 0; i < 16; ++i) {
        float sr = 0.f, si = 0.f;
#pragma unroll
        for (int j = 0; j < 16; ++j) {
            float2 w = Wl[i * 16 + j];   // wave-uniform -> LDS broadcast
            sr += w.x * m[j];
            si += w.y * m[j];
        }
        float pr = sr * sr + si * si;
        z0 += (i & 8) ? -pr : pr;
        z1 += (i & 4) ? -pr : pr;
        z2 += (i & 2) ? -pr : pr;
        z3 += (i & 1) ? -pr : pr;
    }

    float l0 = fc_b[0] + fc_w[0]  * z0 + fc_w[1]  * z1 + fc_w[2]  * z2 + fc_w[3]  * z3;
    float l1 = fc_b[1] + fc_w[4]  * z0 + fc_w[5]  * z1 + fc_w[6]  * z2 + fc_w[7]  * z3;
    float l2 = fc_b[2] + fc_w[8]  * z0 + fc_w[9]  * z1 + fc_w[10] * z2 + fc_w[11] * z3;
    float l3 = fc_b[3] + fc_w[12] * z0 + fc_w[13] * z1 + fc_w[14] * z2 + fc_w[15] * z3;
    out[b] = make_float4(l0, l1, l2, l3);

    // BN partials: sum and sumsq per channel
    float s[8] = { l0, l1, l2, l3, l0 * l0, l1 * l1, l2 * l2, l3 * l3 };
#pragma unroll
    for (int off = 32; off; off >>= 1) {
#pragma unroll
        for (int q = 0; q < 8; ++q) s[q] += __shfl_down(s[q], off);
    }
    __shared__ float red[4][8];
    int wave = tid >> 6, lane = tid & 63;
    if (lane == 0) {
#pragma unroll
        for (int q = 0; q < 8; ++q) red[wave][q] = s[q];
    }
    __syncthreads();
    if (tid < 8) {
        float tot = red[0][tid] + red[1][tid] + red[2][tid] + red[3][tid];
        atomicAdd(&bn_acc[tid], (double)tot);
    }
}

// ---------------------------------------------------------------------------
// Kernel 4: BN finalize in place on d_out.
// ---------------------------------------------------------------------------
__global__ __launch_bounds__(256) void bn_kernel(
        float4* __restrict__ out,
        const double* __restrict__ bn_acc,
        const float* __restrict__ gamma,
        const float* __restrict__ beta) {
    int b = blockIdx.x * 256 + threadIdx.x;
    const double invB = 1.0 / (double)NB;
    float sc[4], sh[4];
#pragma unroll
    for (int k = 0; k < 4; ++k) {
        double mean = bn_acc[k] * invB;
        double var  = bn_acc[4 + k] * invB - mean * mean;
        float inv = (float)(1.0 / sqrt(var + 1e-5));
        float g = gamma[k];
        sc[k] = g * inv;
        sh[k] = beta[k] - (float)mean * g * inv;
    }
    float4 v = out[b];
    v.x = v.x * sc[0] + sh[0];
    v.y = v.y * sc[1] + sh[1];
    v.z = v.z * sc[2] + sh[2];
    v.w = v.w * sc[3] + sh[3];
    out[b] = v;
}

// ---------------------------------------------------------------------------
extern "C" void kernel_launch(void* const* d_in, const int* in_sizes, int n_in,
                              void* d_out, int out_size, void* d_ws, size_t ws_size,
                              hipStream_t stream) {
    const float* x       = (const float*)d_in[0];
    const float* pre_w   = (const float*)d_in[1];
    const float* pre_b   = (const float*)d_in[2];
    const float* weights = (const float*)d_in[3];
    const float* fc_w    = (const float*)d_in[4];
    const float* fc_b    = (const float*)d_in[5];
    const float* gamma   = (const float*)d_in[6];
    const float* beta    = (const float*)d_in[7];

    char* ws = (char*)d_ws;
    float2* W        = (float2*)ws;            // 2048 B
    double* bn_acc   = (double*)(ws + 2048);   // 64 B
    float4* encoded  = (float4*)(ws + 4096);   // NB*16 B = 1 MB

    hipLaunchKernelGGL(build_unitary_kernel, dim3(1), dim3(64), 0, stream,
                       weights, W, bn_acc);
    hipLaunchKernelGGL(pool_fc_kernel, dim3(NB * 4 / 256), dim3(256), 0, stream,
                       x, pre_w, pre_b, encoded);
    hipLaunchKernelGGL(quantum_kernel, dim3(NB / 256), dim3(256), 0, stream,
                       encoded, W, fc_w, fc_b, (float4*)d_out, bn_acc);
    hipLaunchKernelGGL(bn_kernel, dim3(NB / 256), dim3(256), 0, stream,
                       (float4*)d_out, bn_acc, gamma, beta);
}

// Round 2
// 52.905 us; speedup vs baseline: 1.0959x; 1.0959x over previous
//
#include <hip/hip_runtime.h>
#include <math.h>

#define NB 65536   // batch

// ---------------------------------------------------------------------------
// Kernel A: build W = U_layers * diag(zeta_j) (16x16 complex).
// Column-parallel: thread j owns column j of U in registers (fully unrolled
// so all indices are compile-time -> stays in VGPRs).
// ---------------------------------------------------------------------------
__global__ __launch_bounds__(64) void build_unitary_kernel(
        const float* __restrict__ weights,   // [3][4][2]
        float2* __restrict__ W_out) {        // [16*16]
    int t = threadIdx.x;
    if (t >= 16) return;

    float cr[16], ci[16];
#pragma unroll
    for (int i = 0; i < 16; ++i) { cr[i] = (i == t) ? 1.0f : 0.0f; ci[i] = 0.0f; }

    for (int l = 0; l < 3; ++l) {
#pragma unroll
        for (int w = 0; w < 4; ++w) {
            const int mask = 8 >> w;        // wire w -> bit (3-w)
            // RX(weights[l][w][0])
            float tx = weights[(l * 4 + w) * 2 + 0] * 0.5f;
            float c = cosf(tx), s = sinf(tx);
#pragma unroll
            for (int i = 0; i < 16; ++i) {
                if (!(i & mask)) {
                    const int ip = i | mask;
                    float a0r = cr[i], a0i = ci[i], a1r = cr[ip], a1i = ci[ip];
                    // [[c, -i s],[-i s, c]]
                    cr[i]  = c * a0r + s * a1i;
                    ci[i]  = c * a0i - s * a1r;
                    cr[ip] = c * a1r + s * a0i;
                    ci[ip] = c * a1i - s * a0r;
                }
            }
            // RZ(weights[l][w][1]) = diag(e^{-i tz}, e^{+i tz})
            float tz = weights[(l * 4 + w) * 2 + 1] * 0.5f;
            float ce = cosf(tz), se = sinf(tz);
#pragma unroll
            for (int i = 0; i < 16; ++i) {
                if (!(i & mask)) {
                    const int ip = i | mask;
                    float a0r = cr[i], a0i = ci[i], a1r = cr[ip], a1i = ci[ip];
                    cr[i]  = ce * a0r + se * a0i;
                    ci[i]  = ce * a0i - se * a0r;
                    cr[ip] = ce * a1r - se * a1i;
                    ci[ip] = ce * a1i + se * a1r;
                }
            }
        }
        // CNOT ring: control w, target (w+1)%4
#pragma unroll
        for (int w = 0; w < 4; ++w) {
            const int mc = 8 >> w;
            const int mt = 8 >> ((w + 1) & 3);
#pragma unroll
            for (int i = 0; i < 16; ++i) {
                if ((i & mc) && !(i & mt)) {
                    const int ip = i | mt;
                    float tr = cr[i], ti = ci[i];
                    cr[i] = cr[ip]; ci[i] = ci[ip];
                    cr[ip] = tr;   ci[ip] = ti;
                }
            }
        }
    }

    // fold zeta_j = (-i)^popcount(j) into column j
    int p = __popc(t) & 3;
#pragma unroll
    for (int i = 0; i < 16; ++i) {
        float wr, wi;
        if (p == 0)      { wr =  cr[i]; wi =  ci[i]; }
        else if (p == 1) { wr =  ci[i]; wi = -cr[i]; }
        else if (p == 2) { wr = -cr[i]; wi = -ci[i]; }
        else             { wr = -ci[i]; wi =  cr[i]; }
        W_out[i * 16 + t] = make_float2(wr, wi);
    }
}

// ---------------------------------------------------------------------------
// Fused kernel: avg-pool 6x6 + pre-FC + quantum matvec + logits + BN partials.
// Block = 256 threads = 64 images. Pool: 4 threads/image (one 6-row band
// each), shuffle-combine. Quantum: wave 0, one thread per image, W broadcast
// from LDS. Per-block BN partial sums -> d_ws (no atomics).
// ---------------------------------------------------------------------------
__global__ __launch_bounds__(256) void fused_kernel(
        const float* __restrict__ x,        // [B][1][28][28]
        const float* __restrict__ pre_w,    // [4][16]
        const float* __restrict__ pre_b,    // [4]
        const float2* __restrict__ Wu,      // [256]
        const float* __restrict__ fc_w,     // [4][4]
        const float* __restrict__ fc_b,     // [4]
        float4* __restrict__ out,           // [B] logits
        float* __restrict__ partial) {      // [gridDim][8]
    __shared__ float2 Wl[256];
    __shared__ float4 enc[64];
    int tid = threadIdx.x;
    Wl[tid] = Wu[tid];

    int t = blockIdx.x * 256 + tid;
    int b = t >> 2;
    int h1 = t & 3;
    const float* img = x + (size_t)b * 784 + (size_t)(h1 * 6) * 28;

    float cs0 = 0.f, cs1 = 0.f, cs2 = 0.f, cs3 = 0.f;
#pragma unroll
    for (int r = 0; r < 6; ++r) {
        const float4* row = (const float4*)(img + r * 28);  // 16B-aligned
        float4 f0 = row[0], f1 = row[1], f2 = row[2];
        float4 f3 = row[3], f4 = row[4], f5 = row[5];
        cs0 += f0.x + f0.y + f0.z + f0.w + f1.x + f1.y;   // cols 0..5
        cs1 += f1.z + f1.w + f2.x + f2.y + f2.z + f2.w;   // cols 6..11
        cs2 += f3.x + f3.y + f3.z + f3.w + f4.x + f4.y;   // cols 12..17
        cs3 += f4.z + f4.w + f5.x + f5.y + f5.z + f5.w;   // cols 18..23
    }
    const float inv36 = 1.0f / 36.0f;
    cs0 *= inv36; cs1 *= inv36; cs2 *= inv36; cs3 *= inv36;

    const int k0 = h1 * 4;
    float p0 = cs0 * pre_w[0 * 16 + k0] + cs1 * pre_w[0 * 16 + k0 + 1] +
               cs2 * pre_w[0 * 16 + k0 + 2] + cs3 * pre_w[0 * 16 + k0 + 3];
    float p1 = cs0 * pre_w[1 * 16 + k0] + cs1 * pre_w[1 * 16 + k0 + 1] +
               cs2 * pre_w[1 * 16 + k0 + 2] + cs3 * pre_w[1 * 16 + k0 + 3];
    float p2 = cs0 * pre_w[2 * 16 + k0] + cs1 * pre_w[2 * 16 + k0 + 1] +
               cs2 * pre_w[2 * 16 + k0 + 2] + cs3 * pre_w[2 * 16 + k0 + 3];
    float p3 = cs0 * pre_w[3 * 16 + k0] + cs1 * pre_w[3 * 16 + k0 + 1] +
               cs2 * pre_w[3 * 16 + k0 + 2] + cs3 * pre_w[3 * 16 + k0 + 3];

    // combine the 4 bands of one image (lanes 4a..4a+3)
    p0 += __shfl_xor(p0, 1); p0 += __shfl_xor(p0, 2);
    p1 += __shfl_xor(p1, 1); p1 += __shfl_xor(p1, 2);
    p2 += __shfl_xor(p2, 1); p2 += __shfl_xor(p2, 2);
    p3 += __shfl_xor(p3, 1); p3 += __shfl_xor(p3, 2);

    if ((tid & 3) == 0) {
        enc[tid >> 2] = make_float4(p0 + pre_b[0], p1 + pre_b[1],
                                    p2 + pre_b[2], p3 + pre_b[3]);
    }
    __syncthreads();

    if (tid < 64) {
        float4 e = enc[tid];
        float s0, c0, s1, c1, s2, c2, s3, c3;
        __sincosf(e.x * 0.5f, &s0, &c0);
        __sincosf(e.y * 0.5f, &s1, &c1);
        __sincosf(e.z * 0.5f, &s2, &c2);
        __sincosf(e.w * 0.5f, &s3, &c3);

        float m01[4] = { c0 * c1, c0 * s1, s0 * c1, s0 * s1 };
        float m23[4] = { c2 * c3, c2 * s3, s2 * c3, s2 * s3 };
        float m[16];
#pragma unroll
        for (int i = 0; i < 16; ++i) m[i] = m01[i >> 2] * m23[i & 3];

        float z0 = 0.f, z1 = 0.f, z2 = 0.f, z3 = 0.f;
#pragma unroll
        for (int i = 0; i < 16; ++i) {
            float sr = 0.f, si = 0.f;
#pragma unroll
            for (int j = 0; j < 16; ++j) {
                float2 w = Wl[i * 16 + j];   // wave-uniform -> LDS broadcast
                sr += w.x * m[j];
                si += w.y * m[j];
            }
            float pr = sr * sr + si * si;
            z0 += (i & 8) ? -pr : pr;
            z1 += (i & 4) ? -pr : pr;
            z2 += (i & 2) ? -pr : pr;
            z3 += (i & 1) ? -pr : pr;
        }

        float l0 = fc_b[0] + fc_w[0]  * z0 + fc_w[1]  * z1 + fc_w[2]  * z2 + fc_w[3]  * z3;
        float l1 = fc_b[1] + fc_w[4]  * z0 + fc_w[5]  * z1 + fc_w[6]  * z2 + fc_w[7]  * z3;
        float l2 = fc_b[2] + fc_w[8]  * z0 + fc_w[9]  * z1 + fc_w[10] * z2 + fc_w[11] * z3;
        float l3 = fc_b[3] + fc_w[12] * z0 + fc_w[13] * z1 + fc_w[14] * z2 + fc_w[15] * z3;
        out[blockIdx.x * 64 + tid] = make_float4(l0, l1, l2, l3);

        // BN partials over the 64 images of this block (one wave)
        float s[8] = { l0, l1, l2, l3, l0 * l0, l1 * l1, l2 * l2, l3 * l3 };
#pragma unroll
        for (int off = 32; off; off >>= 1) {
#pragma unroll
            for (int q = 0; q < 8; ++q) s[q] += __shfl_down(s[q], off);
        }
        if (tid == 0) {
            float4* p = (float4*)(partial + (size_t)blockIdx.x * 8);
            p[0] = make_float4(s[0], s[1], s[2], s[3]);
            p[1] = make_float4(s[4], s[5], s[6], s[7]);
        }
    }
}

// ---------------------------------------------------------------------------
// Finalize: each block redundantly reduces the 1024x8 partials (L2-resident),
// computes scale/shift per channel, normalizes its 256 images in place.
// ---------------------------------------------------------------------------
__global__ __launch_bounds__(256) void finalize_kernel(
        float4* __restrict__ out,
        const float* __restrict__ partial,   // [1024][8]
        const float* __restrict__ gamma,
        const float* __restrict__ beta) {
    int tid = threadIdx.x;
    float s[8];
#pragma unroll
    for (int q = 0; q < 8; ++q) s[q] = 0.f;
#pragma unroll
    for (int r = 0; r < 4; ++r) {
        const float4* row = (const float4*)(partial + (size_t)(tid + r * 256) * 8);
        float4 a = row[0], c = row[1];
        s[0] += a.x; s[1] += a.y; s[2] += a.z; s[3] += a.w;
        s[4] += c.x; s[5] += c.y; s[6] += c.z; s[7] += c.w;
    }
#pragma unroll
    for (int off = 32; off; off >>= 1) {
#pragma unroll
        for (int q = 0; q < 8; ++q) s[q] += __shfl_down(s[q], off);
    }
    __shared__ float red[4][8];
    __shared__ float tot[8];
    __shared__ float scsh[8];
    int wave = tid >> 6, lane = tid & 63;
    if (lane == 0) {
#pragma unroll
        for (int q = 0; q < 8; ++q) red[wave][q] = s[q];
    }
    __syncthreads();
    if (tid < 8) tot[tid] = red[0][tid] + red[1][tid] + red[2][tid] + red[3][tid];
    __syncthreads();
    if (tid < 4) {
        const float invB = 1.0f / (float)NB;
        float mean = tot[tid] * invB;
        float var  = tot[4 + tid] * invB - mean * mean;
        float inv  = rsqrtf(var + 1e-5f);
        float g = gamma[tid];
        scsh[tid]     = g * inv;                      // scale
        scsh[4 + tid] = beta[tid] - mean * g * inv;   // shift
    }
    __syncthreads();
    float sc0 = scsh[0], sc1 = scsh[1], sc2 = scsh[2], sc3 = scsh[3];
    float sh0 = scsh[4], sh1 = scsh[5], sh2 = scsh[6], sh3 = scsh[7];

    int b = blockIdx.x * 256 + tid;
    float4 v = out[b];
    v.x = v.x * sc0 + sh0;
    v.y = v.y * sc1 + sh1;
    v.z = v.z * sc2 + sh2;
    v.w = v.w * sc3 + sh3;
    out[b] = v;
}

// ---------------------------------------------------------------------------
extern "C" void kernel_launch(void* const* d_in, const int* in_sizes, int n_in,
                              void* d_out, int out_size, void* d_ws, size_t ws_size,
                              hipStream_t stream) {
    const float* x       = (const float*)d_in[0];
    const float* pre_w   = (const float*)d_in[1];
    const float* pre_b   = (const float*)d_in[2];
    const float* weights = (const float*)d_in[3];
    const float* fc_w    = (const float*)d_in[4];
    const float* fc_b    = (const float*)d_in[5];
    const float* gamma   = (const float*)d_in[6];
    const float* beta    = (const float*)d_in[7];

    char* ws = (char*)d_ws;
    float2* W      = (float2*)ws;              // 2048 B
    float* partial = (float*)(ws + 4096);      // 1024*8*4 = 32 KB

    hipLaunchKernelGGL(build_unitary_kernel, dim3(1), dim3(64), 0, stream,
                       weights, W);
    hipLaunchKernelGGL(fused_kernel, dim3(NB / 64), dim3(256), 0, stream,
                       x, pre_w, pre_b, W, fc_w, fc_b, (float4*)d_out, partial);
    hipLaunchKernelGGL(finalize_kernel, dim3(NB / 256), dim3(256), 0, stream,
                       (float4*)d_out, partial, gamma, beta);
}